// Round 4
// baseline (2326.360 us; speedup 1.0000x reference)
//
#include <hip/hip_runtime.h>

#define U_NUM 359347
#define I_NUM 292589
#define DDIM  64
#define NNZ_N 4000000
#define BATCH 32768
#define LAM_F 0.001f
#define ACC_SLOTS 2048

__device__ __forceinline__ float leaky(float x) { return x > 0.f ? x : 0.1f * x; }

__device__ __forceinline__ unsigned short f2bf(float f) {
    unsigned b = __float_as_uint(f);
    b = (b + 0x7FFF + ((b >> 16) & 1)) >> 16;   // RNE
    return (unsigned short)b;
}
__device__ __forceinline__ float bf2f(unsigned short u) {
    return __uint_as_float((unsigned)u << 16);
}

// ---------------------------------------------------------------------------
// fp32 -> bf16 bulk convert (n multiple of 4)
// ---------------------------------------------------------------------------
__global__ __launch_bounds__(256) void f2bf_k(
    const float4* __restrict__ in, ushort4* __restrict__ out, size_t n4)
{
    size_t stride = (size_t)gridDim.x * 256;
    for (size_t i = (size_t)blockIdx.x * 256 + threadIdx.x; i < n4; i += stride) {
        float4 v = in[i];
        ushort4 o;
        o.x = f2bf(v.x); o.y = f2bf(v.y); o.z = f2bf(v.z); o.w = f2bf(v.w);
        out[i] = o;
    }
}

// ---------------------------------------------------------------------------
// CSR build: histogram -> hierarchical exclusive scan -> packed scatter
// ---------------------------------------------------------------------------
__global__ __launch_bounds__(256) void hist_k(
    const int* __restrict__ rows, const int* __restrict__ cols,
    int* __restrict__ cnt_u, int* __restrict__ cnt_i, int nnz)
{
    int e = blockIdx.x * 256 + threadIdx.x;
    if (e >= nnz) return;
    atomicAdd(&cnt_u[rows[e]], 1);
    atomicAdd(&cnt_i[cols[e]], 1);
}

__global__ __launch_bounds__(256) void scan1_k(int* __restrict__ a, int n, int* __restrict__ bsum)
{
    __shared__ int s[256];
    int t = threadIdx.x;
    int base = blockIdx.x * 1024 + t * 4;
    int v[4];
#pragma unroll
    for (int j = 0; j < 4; ++j) v[j] = (base + j < n) ? a[base + j] : 0;
    s[t] = v[0] + v[1] + v[2] + v[3];
    __syncthreads();
    for (int off = 1; off < 256; off <<= 1) {
        int x = (t >= off) ? s[t - off] : 0;
        __syncthreads();
        s[t] += x;
        __syncthreads();
    }
    if (t == 255) bsum[blockIdx.x] = s[255];
    int run = (t > 0) ? s[t - 1] : 0;
#pragma unroll
    for (int j = 0; j < 4; ++j) {
        if (base + j < n) a[base + j] = run;
        run += v[j];
    }
}

__global__ __launch_bounds__(512) void scan2_k(int* __restrict__ bsum, int nb)
{
    __shared__ int s[512];
    int t = threadIdx.x;
    int v = (t < nb) ? bsum[t] : 0;
    s[t] = v;
    __syncthreads();
    for (int off = 1; off < 512; off <<= 1) {
        int x = (t >= off) ? s[t - off] : 0;
        __syncthreads();
        s[t] += x;
        __syncthreads();
    }
    if (t < nb) bsum[t] = s[t] - v;   // exclusive
}

// adds block offset AND writes the running-cursor copy (cur = final ptr)
__global__ __launch_bounds__(256) void scan3_k(int* __restrict__ a, int n,
                                               const int* __restrict__ bsum,
                                               int* __restrict__ cur)
{
    int add = bsum[blockIdx.x];
    int base = blockIdx.x * 1024 + threadIdx.x * 4;
#pragma unroll
    for (int j = 0; j < 4; ++j)
        if (base + j < n) {
            int v = a[base + j] + add;
            a[base + j] = v;
            cur[base + j] = v;
        }
}

// packed scatter: one atomicAdd + one 8B store per edge per side
__global__ __launch_bounds__(256) void scatter_k(
    const int* __restrict__ rows, const int* __restrict__ cols,
    const float* __restrict__ uv, const float* __restrict__ iv,
    int* __restrict__ cur_u, int* __restrict__ cur_i,
    int2* __restrict__ cu_ent, int2* __restrict__ ci_ent, int nnz)
{
    int e = blockIdx.x * 256 + threadIdx.x;
    if (e >= nnz) return;
    int r = rows[e], c = cols[e];
    int pu = atomicAdd(&cur_u[r], 1);
    cu_ent[pu] = make_int2(c, __float_as_int(uv[e]));
    int pi = atomicAdd(&cur_i[c], 1);
    ci_ent[pi] = make_int2(r, __float_as_int(iv[e]));
}

// ---------------------------------------------------------------------------
// CSR SpMM over bf16 matrices, one wave per row (lane = dim).
// MODE 0: out = relu(A@x + base*deg)                         (layer 1)
// MODE 1: g2 = relu(A@x + base*deg);
//         out = w0*embed + w1*base + w2*g2; accumulate sum(out^2). (layer 2)
// base/out may alias (in-place combine) -> no __restrict__ on them.
// ---------------------------------------------------------------------------
template <int MODE>
__global__ __launch_bounds__(256) void spmm_csr_k(
    const int* __restrict__ ptr, const int2* __restrict__ ent,
    const unsigned short* __restrict__ x, const unsigned short* base,
    const float* __restrict__ deg, unsigned short* out, int nrows,
    const unsigned short* __restrict__ embed, const float* __restrict__ add_w,
    float* __restrict__ accArr)
{
    int wv = threadIdx.x >> 6, lane = threadIdx.x & 63;
    int r = blockIdx.x * 4 + wv;
    __shared__ float ssum[4];
    if (r < nrows) {
        int s0 = __builtin_amdgcn_readfirstlane(ptr[r]);
        int e0 = __builtin_amdgcn_readfirstlane(ptr[r + 1]);
        float a0 = 0.f, a1 = 0.f, a2 = 0.f, a3 = 0.f;
        int k = s0;
        for (; k + 4 <= e0; k += 4) {
            int2 q0 = ent[k], q1 = ent[k + 1], q2 = ent[k + 2], q3 = ent[k + 3];
            float x0 = bf2f(x[(size_t)q0.x * DDIM + lane]);
            float x1 = bf2f(x[(size_t)q1.x * DDIM + lane]);
            float x2 = bf2f(x[(size_t)q2.x * DDIM + lane]);
            float x3 = bf2f(x[(size_t)q3.x * DDIM + lane]);
            a0 = fmaf(__int_as_float(q0.y), x0, a0);
            a1 = fmaf(__int_as_float(q1.y), x1, a1);
            a2 = fmaf(__int_as_float(q2.y), x2, a2);
            a3 = fmaf(__int_as_float(q3.y), x3, a3);
        }
        for (; k < e0; ++k) {
            int2 q = ent[k];
            a0 = fmaf(__int_as_float(q.y), bf2f(x[(size_t)q.x * DDIM + lane]), a0);
        }
        float acc = (a0 + a1) + (a2 + a3);
        float bb = bf2f(base[(size_t)r * DDIM + lane]);
        float o = fmaxf(fmaf(bb, deg[r], acc), 0.f);
        if (MODE == 0) {
            out[(size_t)r * DDIM + lane] = f2bf(o);
        } else {
            float g = fmaf(add_w[0], bf2f(embed[(size_t)r * DDIM + lane]),
                           fmaf(add_w[1], bb, add_w[2] * o));
            out[(size_t)r * DDIM + lane] = f2bf(g);
            float sq = g * g;
            for (int off = 32; off; off >>= 1) sq += __shfl_down(sq, off);
            if (lane == 0) ssum[wv] = sq;
        }
    } else if (MODE == 1) {
        if (lane == 0) ssum[wv] = 0.f;
    }
    if (MODE == 1) {
        __syncthreads();
        if (threadIdx.x == 0)
            atomicAdd(&accArr[blockIdx.x & (ACC_SLOTS - 1)],
                      ssum[0] + ssum[1] + ssum[2] + ssum[3]);
    }
}

// ---------------------------------------------------------------------------
// Batch MLP: LDS-staged transposed weights, 1 wave = 1 sample (both sides),
// grid-stride. Inputs are pre-combined bf16 gcn rows.
// ---------------------------------------------------------------------------
__global__ __launch_bounds__(256) void batch_mlp2_k(
    const int* __restrict__ user0, const int* __restrict__ item0,
    const unsigned short* __restrict__ gcnU, const unsigned short* __restrict__ gcnI,
    const float* __restrict__ fw1, const float* __restrict__ fb1,
    const float* __restrict__ fw2, const float* __restrict__ fb2,
    const float* __restrict__ ub, const float* __restrict__ ib,
    const float* __restrict__ avg, const float* __restrict__ ratings,
    float* __restrict__ sse_acc)
{
    __shared__ float2 w1p[64][64];   // [d][o] -> (fw1[o][d], fw1[o+64][d])
    __shared__ float  w2T[128][64];  // [k][o] -> fw2[o][k]
    for (int i = threadIdx.x; i < 8192; i += 256) {
        int o = i >> 6, d = i & 63;
        float v = fw1[i];
        if (o < 64) w1p[d][o].x = v; else w1p[d][o - 64].y = v;
        int oo = i >> 7, kk = i & 127;
        w2T[kk][oo] = fw2[i];
    }
    __syncthreads();
    int wv = threadIdx.x >> 6, lane = threadIdx.x & 63;
    float b1a = fb1[lane], b1b = fb1[lane + 64], b2 = fb2[lane];
    float avgv = avg[0];
    float lsum = 0.f;
    for (int b = blockIdx.x * 4 + wv; b < BATCH; b += gridDim.x * 4) {
        int uidx = user0[b], iidx = item0[b];
        float xu = bf2f(gcnU[(size_t)uidx * DDIM + lane]);
        float xi = bf2f(gcnI[(size_t)iidx * DDIM + lane]);
        float hu0 = b1a, hu1 = b1b, hi0 = b1a, hi1 = b1b;
#pragma unroll
        for (int d = 0; d < 64; ++d) {
            float2 w = w1p[d][lane];
            float xud = __shfl(xu, d);
            float xid = __shfl(xi, d);
            hu0 = fmaf(w.x, xud, hu0);
            hu1 = fmaf(w.y, xud, hu1);
            hi0 = fmaf(w.x, xid, hi0);
            hi1 = fmaf(w.y, xid, hi1);
        }
        hu0 = leaky(hu0); hu1 = leaky(hu1);
        hi0 = leaky(hi0); hi1 = leaky(hi1);
        float ou = b2, oi = b2;
#pragma unroll
        for (int kk = 0; kk < 64; ++kk) {
            float w = w2T[kk][lane];
            ou = fmaf(w, __shfl(hu0, kk), ou);
            oi = fmaf(w, __shfl(hi0, kk), oi);
        }
#pragma unroll
        for (int kk = 0; kk < 64; ++kk) {
            float w = w2T[kk + 64][lane];
            ou = fmaf(w, __shfl(hu1, kk), ou);
            oi = fmaf(w, __shfl(hi1, kk), oi);
        }
        ou = leaky(ou); oi = leaky(oi);
        float p = ou * oi;
        for (int off = 32; off; off >>= 1) p += __shfl_down(p, off);
        if (lane == 0) {
            float pred = p + ub[uidx] + ib[iidx] + avgv;
            float diff = pred - ratings[b];
            lsum = fmaf(diff, diff, lsum);
        }
    }
    __shared__ float s_p[4];
    if (lane == 0) s_p[wv] = lsum;
    __syncthreads();
    if (threadIdx.x == 0)
        atomicAdd(sse_acc, s_p[0] + s_p[1] + s_p[2] + s_p[3]);
}

__global__ __launch_bounds__(256) void finalize2_k(
    const float* __restrict__ accU, const float* __restrict__ accI,
    const float* __restrict__ sse, float* __restrict__ out)
{
    int t = threadIdx.x;
    float su = 0.f, si = 0.f;
    for (int i = t; i < ACC_SLOTS; i += 256) { su += accU[i]; si += accI[i]; }
    for (int off = 32; off; off >>= 1) {
        su += __shfl_down(su, off);
        si += __shfl_down(si, off);
    }
    __shared__ float s[8];
    int wv = t >> 6, lane = t & 63;
    if (lane == 0) { s[wv] = su; s[wv + 4] = si; }
    __syncthreads();
    if (t == 0) {
        float SU = s[0] + s[1] + s[2] + s[3];
        float SI = s[4] + s[5] + s[6] + s[7];
        out[0] = sse[0] / (float)BATCH
               + LAM_F * (SU / (float)((double)U_NUM * 64.0))
               + LAM_F * (SI / (float)((double)I_NUM * 64.0));
    }
}

// ---------------------------------------------------------------------------

extern "C" void kernel_launch(void* const* d_in, const int* in_sizes, int n_in,
                              void* d_out, int out_size, void* d_ws, size_t ws_size,
                              hipStream_t stream)
{
    const int*   ui_rows = (const int*)d_in[0];
    const int*   ui_cols = (const int*)d_in[1];
    const float* ui_vals = (const float*)d_in[2];
    const float* iu_vals = (const float*)d_in[3];
    const float* d_i     = (const float*)d_in[4];
    const float* d_j     = (const float*)d_in[5];
    const float* eu      = (const float*)d_in[6];
    const float* ei      = (const float*)d_in[7];
    const float* add_w   = (const float*)d_in[8];
    const float* fw1     = (const float*)d_in[9];
    const float* fb1     = (const float*)d_in[10];
    const float* fw2     = (const float*)d_in[11];
    const float* fb2     = (const float*)d_in[12];
    const float* ub      = (const float*)d_in[13];
    const float* ib      = (const float*)d_in[14];
    const float* avg     = (const float*)d_in[15];
    const int*   user0   = (const int*)d_in[16];
    const int*   item0   = (const int*)d_in[17];
    const float* ratings = (const float*)d_in[18];

    const size_t U64 = (size_t)U_NUM * DDIM;   // 22,998,208 (mult of 4)
    const size_t I64 = (size_t)I_NUM * DDIM;   // 18,725,696 (mult of 4)

    // ---- layout (~274 MB) ----
    int2* cu_ent = (int2*)d_ws;                    // NNZ
    int2* ci_ent = cu_ent + NNZ_N;                 // NNZ
    int*  meta   = (int*)(ci_ent + NNZ_N);
    int*  ptr_u  = meta;                           // U+1
    int*  ptr_i  = ptr_u + (U_NUM + 1);            // I+1
    int*  cur_u  = ptr_i + (I_NUM + 1);            // U+1
    int*  cur_i  = cur_u + (U_NUM + 1);            // I+1
    int*  bsumU  = cur_i + (I_NUM + 1);            // 512
    int*  bsumI  = bsumU + 512;                    // 512
    float* accU  = (float*)(bsumI + 512);          // ACC_SLOTS
    float* accI  = accU + ACC_SLOTS;               // ACC_SLOTS
    float* sse   = accI + ACC_SLOTS;               // 4
    size_t meta_ints = 2 * (size_t)(U_NUM + 1) + 2 * (I_NUM + 1)
                     + 1024 + 2 * ACC_SLOTS + 4;
    unsigned short* eu_bf  = (unsigned short*)(meta + meta_ints);  // U64
    unsigned short* ei_bf  = eu_bf + U64;                          // I64
    unsigned short* g1u_bf = ei_bf + I64;                          // U64 (becomes gcnU)
    unsigned short* g1i_bf = g1u_bf + U64;                         // I64
    unsigned short* gcnI_bf = g1i_bf + I64;                        // I64
    size_t needed = ((char*)(gcnI_bf + I64)) - (char*)d_ws;
    (void)ws_size; (void)needed;   // ~274 MB; known to fit (311 MB path ran)

    dim3 blk(256);

    // zero hist counters + acc slots (cur_* rewritten by scan3)
    hipMemsetAsync(meta, 0, meta_ints * sizeof(int), stream);

    // bf16 copies of the embeddings
    f2bf_k<<<2048, blk, 0, stream>>>((const float4*)eu, (ushort4*)eu_bf, U64 / 4);
    f2bf_k<<<2048, blk, 0, stream>>>((const float4*)ei, (ushort4*)ei_bf, I64 / 4);

    int eg = (NNZ_N + 255) / 256;
    hist_k<<<eg, blk, 0, stream>>>(ui_rows, ui_cols, ptr_u, ptr_i, NNZ_N);

    int nU = U_NUM + 1, nI = I_NUM + 1;
    int nbU = (nU + 1023) / 1024, nbI = (nI + 1023) / 1024;
    scan1_k<<<nbU, blk, 0, stream>>>(ptr_u, nU, bsumU);
    scan2_k<<<1, 512, 0, stream>>>(bsumU, nbU);
    scan3_k<<<nbU, blk, 0, stream>>>(ptr_u, nU, bsumU, cur_u);
    scan1_k<<<nbI, blk, 0, stream>>>(ptr_i, nI, bsumI);
    scan2_k<<<1, 512, 0, stream>>>(bsumI, nbI);
    scan3_k<<<nbI, blk, 0, stream>>>(ptr_i, nI, bsumI, cur_i);

    scatter_k<<<eg, blk, 0, stream>>>(ui_rows, ui_cols, ui_vals, iu_vals,
                                      cur_u, cur_i, cu_ent, ci_ent, NNZ_N);

    int gu = (U_NUM + 3) / 4, gi = (I_NUM + 3) / 4;
    // layer 1
    spmm_csr_k<0><<<gu, blk, 0, stream>>>(ptr_u, cu_ent, ei_bf, eu_bf, d_i,
                                          g1u_bf, U_NUM, nullptr, nullptr, nullptr);
    spmm_csr_k<0><<<gi, blk, 0, stream>>>(ptr_i, ci_ent, eu_bf, ei_bf, d_j,
                                          g1i_bf, I_NUM, nullptr, nullptr, nullptr);
    // layer 2 + combine + fused L2 partials
    // gcn_i first (x = g1u intact), then gcn_u in-place over g1u (x = g1i)
    spmm_csr_k<1><<<gi, blk, 0, stream>>>(ptr_i, ci_ent, g1u_bf, g1i_bf, d_j,
                                          gcnI_bf, I_NUM, ei_bf, add_w, accI);
    spmm_csr_k<1><<<gu, blk, 0, stream>>>(ptr_u, cu_ent, g1i_bf, g1u_bf, d_i,
                                          g1u_bf, U_NUM, eu_bf, add_w, accU);

    batch_mlp2_k<<<1024, blk, 0, stream>>>(user0, item0, g1u_bf, gcnI_bf,
                                           fw1, fb1, fw2, fb2, ub, ib, avg,
                                           ratings, sse);
    finalize2_k<<<1, blk, 0, stream>>>(accU, accI, sse, (float*)d_out);
}

// Round 6
// 1739.340 us; speedup vs baseline: 1.3375x; 1.3375x over previous
//
#include <hip/hip_runtime.h>

#define U_NUM 359347
#define I_NUM 292589
#define DDIM  64
#define NNZ_N 4000000
#define BATCH 32768
#define LAM_F 0.001f
#define ACC_SLOTS 2048

#define EPB   4096                          // edges per level-1 block
#define NBLK  ((NNZ_N + EPB - 1) / EPB)     // 977
#define NB_U  ((U_NUM + 1023) >> 10)        // 351
#define NB_I  ((I_NUM + 1023) >> 10)        // 286

__device__ __forceinline__ float leaky(float x) { return x > 0.f ? x : 0.1f * x; }

__device__ __forceinline__ unsigned short f2bf(float f) {
    unsigned b = __float_as_uint(f);
    b = (b + 0x7FFF + ((b >> 16) & 1)) >> 16;   // RNE
    return (unsigned short)b;
}
__device__ __forceinline__ float bf2f(unsigned short u) {
    return __uint_as_float((unsigned)u << 16);
}

// ---------------------------------------------------------------------------
// fp32 -> bf16 bulk convert
// ---------------------------------------------------------------------------
__global__ __launch_bounds__(256) void f2bf_k(
    const float4* __restrict__ in, ushort4* __restrict__ out, size_t n4)
{
    size_t stride = (size_t)gridDim.x * 256;
    for (size_t i = (size_t)blockIdx.x * 256 + threadIdx.x; i < n4; i += stride) {
        float4 v = in[i];
        ushort4 o;
        o.x = f2bf(v.x); o.y = f2bf(v.y); o.z = f2bf(v.z); o.w = f2bf(v.w);
        out[i] = o;
    }
}

// ---------------------------------------------------------------------------
// Level-1: bucket histogram per block  (bucket = key >> 10)
// gh layout: gh[bucket * NBLK + block]
// ---------------------------------------------------------------------------
__global__ __launch_bounds__(256) void l1hist_k(
    const int* __restrict__ keys, int* __restrict__ gh, int nb)
{
    __shared__ int h[512];
    for (int i = threadIdx.x; i < nb; i += 256) h[i] = 0;
    __syncthreads();
    int base = blockIdx.x * EPB;
    int end = min(base + EPB, NNZ_N);
    for (int e = base + threadIdx.x; e < end; e += 256)
        atomicAdd(&h[keys[e] >> 10], 1);
    __syncthreads();
    for (int i = threadIdx.x; i < nb; i += 256)
        gh[i * NBLK + blockIdx.x] = h[i];
}

// ---------------------------------------------------------------------------
// exclusive scan over gh (in-place), 1024 elems/block
// ---------------------------------------------------------------------------
__global__ __launch_bounds__(256) void scan1_k(int* __restrict__ a, int n, int* __restrict__ bsum)
{
    __shared__ int s[256];
    int t = threadIdx.x;
    int base = blockIdx.x * 1024 + t * 4;
    int v[4];
#pragma unroll
    for (int j = 0; j < 4; ++j) v[j] = (base + j < n) ? a[base + j] : 0;
    s[t] = v[0] + v[1] + v[2] + v[3];
    __syncthreads();
    for (int off = 1; off < 256; off <<= 1) {
        int x = (t >= off) ? s[t - off] : 0;
        __syncthreads();
        s[t] += x;
        __syncthreads();
    }
    if (t == 255) bsum[blockIdx.x] = s[255];
    int run = (t > 0) ? s[t - 1] : 0;
#pragma unroll
    for (int j = 0; j < 4; ++j) {
        if (base + j < n) a[base + j] = run;
        run += v[j];
    }
}

__global__ __launch_bounds__(512) void scan2_k(int* __restrict__ bsum, int nb)
{
    __shared__ int s[512];
    int t = threadIdx.x;
    int v = (t < nb) ? bsum[t] : 0;
    s[t] = v;
    __syncthreads();
    for (int off = 1; off < 512; off <<= 1) {
        int x = (t >= off) ? s[t - off] : 0;
        __syncthreads();
        s[t] += x;
        __syncthreads();
    }
    if (t < nb) bsum[t] = s[t] - v;   // exclusive
}

__global__ __launch_bounds__(256) void scan3_k(int* __restrict__ a, int n,
                                               const int* __restrict__ bsum)
{
    int add = bsum[blockIdx.x];
    int base = blockIdx.x * 1024 + threadIdx.x * 4;
#pragma unroll
    for (int j = 0; j < 4; ++j)
        if (base + j < n) a[base + j] += add;
}

// ---------------------------------------------------------------------------
// Level-1 scatter: (key, eid) -> tmp, each block owns contiguous pre-scanned
// sub-ranges per bucket (burst-coalesced writes, no global atomics)
// ---------------------------------------------------------------------------
__global__ __launch_bounds__(256) void l1scatter_k(
    const int* __restrict__ keys, const int* __restrict__ gh, int nb,
    int2* __restrict__ out)
{
    __shared__ int cur[512];
    for (int i = threadIdx.x; i < nb; i += 256) cur[i] = gh[i * NBLK + blockIdx.x];
    __syncthreads();
    int base = blockIdx.x * EPB;
    int end = min(base + EPB, NNZ_N);
    for (int e = base + threadIdx.x; e < end; e += 256) {
        int k = keys[e];
        int pos = atomicAdd(&cur[k >> 10], 1);
        out[pos] = make_int2(k, e);
    }
}

// ---------------------------------------------------------------------------
// Level-2: one block per bucket. LDS counting sort over the bucket's 1024
// rows; emits ptr[] and final packed (col,val) CSR entries (L2-local writes).
// ---------------------------------------------------------------------------
__global__ __launch_bounds__(256) void l2sort_k(
    const int2* __restrict__ tmp, const int* __restrict__ gh, int nb,
    const int* __restrict__ colArr, const float* __restrict__ valArr,
    int* __restrict__ ptr, int nrows, int2* __restrict__ ent)
{
    __shared__ int hist[1024];
    __shared__ int ssc[256];
    int b = blockIdx.x;
    int t = threadIdx.x;
    int bucket_base = gh[b * NBLK];
    int bucket_end  = (b == nb - 1) ? NNZ_N : gh[(b + 1) * NBLK];
    for (int i = t; i < 1024; i += 256) hist[i] = 0;
    __syncthreads();
    for (int e = bucket_base + t; e < bucket_end; e += 256)
        atomicAdd(&hist[tmp[e].x & 1023], 1);
    __syncthreads();
    // exclusive scan of hist[1024]
    int v0 = hist[t * 4], v1 = hist[t * 4 + 1], v2 = hist[t * 4 + 2], v3 = hist[t * 4 + 3];
    ssc[t] = v0 + v1 + v2 + v3;
    __syncthreads();
    for (int off = 1; off < 256; off <<= 1) {
        int x = (t >= off) ? ssc[t - off] : 0;
        __syncthreads();
        ssc[t] += x;
        __syncthreads();
    }
    int run = (t > 0) ? ssc[t - 1] : 0;
    int g0 = run, g1 = run + v0, g2 = g1 + v1, g3 = g2 + v2;
    hist[t * 4] = g0; hist[t * 4 + 1] = g1; hist[t * 4 + 2] = g2; hist[t * 4 + 3] = g3;
    // emit ptr for this bucket's rows
    int rbase = b << 10;
    if (rbase + t * 4 < nrows)     ptr[rbase + t * 4]     = bucket_base + g0;
    if (rbase + t * 4 + 1 < nrows) ptr[rbase + t * 4 + 1] = bucket_base + g1;
    if (rbase + t * 4 + 2 < nrows) ptr[rbase + t * 4 + 2] = bucket_base + g2;
    if (rbase + t * 4 + 3 < nrows) ptr[rbase + t * 4 + 3] = bucket_base + g3;
    if (b == nb - 1 && t == 0) ptr[nrows] = NNZ_N;
    __syncthreads();   // hist[] now = in-bucket cursors
    for (int e = bucket_base + t; e < bucket_end; e += 256) {
        int2 q = tmp[e];
        int pos = bucket_base + atomicAdd(&hist[q.x & 1023], 1);
        ent[pos] = make_int2(colArr[q.y], __float_as_int(valArr[q.y]));
    }
}

// ---------------------------------------------------------------------------
// CSR SpMM over bf16 matrices, one wave per row (lane = dim).
// MODE 0: out = relu(A@x + base*deg)
// MODE 1: g2 = relu(A@x + base*deg); out = w0*embed + w1*base + w2*g2;
//         accumulate sum(out^2) into accArr.  base/out may alias.
// ---------------------------------------------------------------------------
template <int MODE>
__global__ __launch_bounds__(256) void spmm_csr_k(
    const int* __restrict__ ptr, const int2* __restrict__ ent,
    const unsigned short* __restrict__ x, const unsigned short* base,
    const float* __restrict__ deg, unsigned short* out, int nrows,
    const unsigned short* __restrict__ embed, const float* __restrict__ add_w,
    float* __restrict__ accArr)
{
    int wv = threadIdx.x >> 6, lane = threadIdx.x & 63;
    int r = blockIdx.x * 4 + wv;
    __shared__ float ssum[4];
    if (r < nrows) {
        int s0 = __builtin_amdgcn_readfirstlane(ptr[r]);
        int e0 = __builtin_amdgcn_readfirstlane(ptr[r + 1]);
        float a0 = 0.f, a1 = 0.f, a2 = 0.f, a3 = 0.f;
        int k = s0;
        for (; k + 4 <= e0; k += 4) {
            int2 q0 = ent[k], q1 = ent[k + 1], q2 = ent[k + 2], q3 = ent[k + 3];
            float x0 = bf2f(x[(size_t)q0.x * DDIM + lane]);
            float x1 = bf2f(x[(size_t)q1.x * DDIM + lane]);
            float x2 = bf2f(x[(size_t)q2.x * DDIM + lane]);
            float x3 = bf2f(x[(size_t)q3.x * DDIM + lane]);
            a0 = fmaf(__int_as_float(q0.y), x0, a0);
            a1 = fmaf(__int_as_float(q1.y), x1, a1);
            a2 = fmaf(__int_as_float(q2.y), x2, a2);
            a3 = fmaf(__int_as_float(q3.y), x3, a3);
        }
        for (; k < e0; ++k) {
            int2 q = ent[k];
            a0 = fmaf(__int_as_float(q.y), bf2f(x[(size_t)q.x * DDIM + lane]), a0);
        }
        float acc = (a0 + a1) + (a2 + a3);
        float bb = bf2f(base[(size_t)r * DDIM + lane]);
        float o = fmaxf(fmaf(bb, deg[r], acc), 0.f);
        if (MODE == 0) {
            out[(size_t)r * DDIM + lane] = f2bf(o);
        } else {
            float g = fmaf(add_w[0], bf2f(embed[(size_t)r * DDIM + lane]),
                           fmaf(add_w[1], bb, add_w[2] * o));
            out[(size_t)r * DDIM + lane] = f2bf(g);
            float sq = g * g;
            for (int off = 32; off; off >>= 1) sq += __shfl_down(sq, off);
            if (lane == 0) ssum[wv] = sq;
        }
    } else if (MODE == 1) {
        if (lane == 0) ssum[wv] = 0.f;
    }
    if (MODE == 1) {
        __syncthreads();
        if (threadIdx.x == 0)
            atomicAdd(&accArr[blockIdx.x & (ACC_SLOTS - 1)],
                      ssum[0] + ssum[1] + ssum[2] + ssum[3]);
    }
}

// ---------------------------------------------------------------------------
// Batch MLP: LDS-staged transposed weights, 1 wave = 1 sample (both sides),
// grid-stride. Inputs are pre-combined bf16 gcn rows.
// ---------------------------------------------------------------------------
__global__ __launch_bounds__(256) void batch_mlp2_k(
    const int* __restrict__ user0, const int* __restrict__ item0,
    const unsigned short* __restrict__ gcnU, const unsigned short* __restrict__ gcnI,
    const float* __restrict__ fw1, const float* __restrict__ fb1,
    const float* __restrict__ fw2, const float* __restrict__ fb2,
    const float* __restrict__ ub, const float* __restrict__ ib,
    const float* __restrict__ avg, const float* __restrict__ ratings,
    float* __restrict__ sse_acc)
{
    __shared__ float2 w1p[64][64];
    __shared__ float  w2T[128][64];
    for (int i = threadIdx.x; i < 8192; i += 256) {
        int o = i >> 6, d = i & 63;
        float v = fw1[i];
        if (o < 64) w1p[d][o].x = v; else w1p[d][o - 64].y = v;
        int oo = i >> 7, kk = i & 127;
        w2T[kk][oo] = fw2[i];
    }
    __syncthreads();
    int wv = threadIdx.x >> 6, lane = threadIdx.x & 63;
    float b1a = fb1[lane], b1b = fb1[lane + 64], b2 = fb2[lane];
    float avgv = avg[0];
    float lsum = 0.f;
    for (int b = blockIdx.x * 4 + wv; b < BATCH; b += gridDim.x * 4) {
        int uidx = user0[b], iidx = item0[b];
        float xu = bf2f(gcnU[(size_t)uidx * DDIM + lane]);
        float xi = bf2f(gcnI[(size_t)iidx * DDIM + lane]);
        float hu0 = b1a, hu1 = b1b, hi0 = b1a, hi1 = b1b;
#pragma unroll
        for (int d = 0; d < 64; ++d) {
            float2 w = w1p[d][lane];
            float xud = __shfl(xu, d);
            float xid = __shfl(xi, d);
            hu0 = fmaf(w.x, xud, hu0);
            hu1 = fmaf(w.y, xud, hu1);
            hi0 = fmaf(w.x, xid, hi0);
            hi1 = fmaf(w.y, xid, hi1);
        }
        hu0 = leaky(hu0); hu1 = leaky(hu1);
        hi0 = leaky(hi0); hi1 = leaky(hi1);
        float ou = b2, oi = b2;
#pragma unroll
        for (int kk = 0; kk < 64; ++kk) {
            float w = w2T[kk][lane];
            ou = fmaf(w, __shfl(hu0, kk), ou);
            oi = fmaf(w, __shfl(hi0, kk), oi);
        }
#pragma unroll
        for (int kk = 0; kk < 64; ++kk) {
            float w = w2T[kk + 64][lane];
            ou = fmaf(w, __shfl(hu1, kk), ou);
            oi = fmaf(w, __shfl(hi1, kk), oi);
        }
        ou = leaky(ou); oi = leaky(oi);
        float p = ou * oi;
        for (int off = 32; off; off >>= 1) p += __shfl_down(p, off);
        if (lane == 0) {
            float pred = p + ub[uidx] + ib[iidx] + avgv;
            float diff = pred - ratings[b];
            lsum = fmaf(diff, diff, lsum);
        }
    }
    __shared__ float s_p[4];
    if (lane == 0) s_p[wv] = lsum;
    __syncthreads();
    if (threadIdx.x == 0)
        atomicAdd(sse_acc, s_p[0] + s_p[1] + s_p[2] + s_p[3]);
}

__global__ __launch_bounds__(256) void finalize2_k(
    const float* __restrict__ accU, const float* __restrict__ accI,
    const float* __restrict__ sse, float* __restrict__ out)
{
    int t = threadIdx.x;
    float su = 0.f, si = 0.f;
    for (int i = t; i < ACC_SLOTS; i += 256) { su += accU[i]; si += accI[i]; }
    for (int off = 32; off; off >>= 1) {
        su += __shfl_down(su, off);
        si += __shfl_down(si, off);
    }
    __shared__ float s[8];
    int wv = t >> 6, lane = t & 63;
    if (lane == 0) { s[wv] = su; s[wv + 4] = si; }
    __syncthreads();
    if (t == 0) {
        float SU = s[0] + s[1] + s[2] + s[3];
        float SI = s[4] + s[5] + s[6] + s[7];
        out[0] = sse[0] / (float)BATCH
               + LAM_F * (SU / (float)((double)U_NUM * 64.0))
               + LAM_F * (SI / (float)((double)I_NUM * 64.0));
    }
}

// ---------------------------------------------------------------------------

extern "C" void kernel_launch(void* const* d_in, const int* in_sizes, int n_in,
                              void* d_out, int out_size, void* d_ws, size_t ws_size,
                              hipStream_t stream)
{
    const int*   ui_rows = (const int*)d_in[0];
    const int*   ui_cols = (const int*)d_in[1];
    const float* ui_vals = (const float*)d_in[2];
    const float* iu_vals = (const float*)d_in[3];
    const float* d_i     = (const float*)d_in[4];
    const float* d_j     = (const float*)d_in[5];
    const float* eu      = (const float*)d_in[6];
    const float* ei      = (const float*)d_in[7];
    const float* add_w   = (const float*)d_in[8];
    const float* fw1     = (const float*)d_in[9];
    const float* fb1     = (const float*)d_in[10];
    const float* fw2     = (const float*)d_in[11];
    const float* fb2     = (const float*)d_in[12];
    const float* ub      = (const float*)d_in[13];
    const float* ib      = (const float*)d_in[14];
    const float* avg     = (const float*)d_in[15];
    const int*   user0   = (const int*)d_in[16];
    const int*   item0   = (const int*)d_in[17];
    const float* ratings = (const float*)d_in[18];

    const size_t U64 = (size_t)U_NUM * DDIM;
    const size_t I64 = (size_t)I_NUM * DDIM;

    // ---- workspace layout (~305 MB; budget known >= 334 MB) ----
    int2* ent_u = (int2*)d_ws;                       // NNZ
    int2* ent_i = ent_u + NNZ_N;                     // NNZ
    int2* tmpb  = ent_i + NNZ_N;                     // NNZ (shared by both sides)
    int*  gh    = (int*)(tmpb + NNZ_N);              // NB_U * NBLK (max)
    int*  bsum  = gh + (size_t)NB_U * NBLK;          // 512
    int*  ptr_u = bsum + 512;                        // U+1
    int*  ptr_i = ptr_u + (U_NUM + 1);               // I+1
    float* accU = (float*)(ptr_i + (I_NUM + 1));     // ACC_SLOTS
    float* accI = accU + ACC_SLOTS;                  // ACC_SLOTS
    float* sse  = accI + ACC_SLOTS;                  // 4
    unsigned short* eu_bf   = (unsigned short*)(sse + 4);  // U64
    unsigned short* ei_bf   = eu_bf + U64;                 // I64
    unsigned short* g1u_bf  = ei_bf + I64;                 // U64 (becomes gcnU)
    unsigned short* g1i_bf  = g1u_bf + U64;                // I64
    unsigned short* gcnI_bf = g1i_bf + I64;                // I64
    (void)ws_size;

    dim3 blk(256);
    int gu = (U_NUM + 3) / 4, gi = (I_NUM + 3) / 4;

    hipMemsetAsync(accU, 0, (2 * ACC_SLOTS + 4) * sizeof(float), stream);

    f2bf_k<<<2048, blk, 0, stream>>>((const float4*)eu, (ushort4*)eu_bf, U64 / 4);
    f2bf_k<<<2048, blk, 0, stream>>>((const float4*)ei, (ushort4*)ei_bf, I64 / 4);

    // ---- user-side CSR (key = ui_rows) ----
    {
        int n = NB_U * NBLK;
        int nb1 = (n + 1023) / 1024;
        l1hist_k<<<NBLK, blk, 0, stream>>>(ui_rows, gh, NB_U);
        scan1_k<<<nb1, blk, 0, stream>>>(gh, n, bsum);
        scan2_k<<<1, 512, 0, stream>>>(bsum, nb1);
        scan3_k<<<nb1, blk, 0, stream>>>(gh, n, bsum);
        l1scatter_k<<<NBLK, blk, 0, stream>>>(ui_rows, gh, NB_U, tmpb);
        l2sort_k<<<NB_U, blk, 0, stream>>>(tmpb, gh, NB_U, ui_cols, ui_vals,
                                           ptr_u, U_NUM, ent_u);
    }
    // ---- item-side CSR (key = ui_cols) ----
    {
        int n = NB_I * NBLK;
        int nb1 = (n + 1023) / 1024;
        l1hist_k<<<NBLK, blk, 0, stream>>>(ui_cols, gh, NB_I);
        scan1_k<<<nb1, blk, 0, stream>>>(gh, n, bsum);
        scan2_k<<<1, 512, 0, stream>>>(bsum, nb1);
        scan3_k<<<nb1, blk, 0, stream>>>(gh, n, bsum);
        l1scatter_k<<<NBLK, blk, 0, stream>>>(ui_cols, gh, NB_I, tmpb);
        l2sort_k<<<NB_I, blk, 0, stream>>>(tmpb, gh, NB_I, ui_rows, iu_vals,
                                           ptr_i, I_NUM, ent_i);
    }

    // ---- GCN layers ----
    // layer 1
    spmm_csr_k<0><<<gu, blk, 0, stream>>>(ptr_u, ent_u, ei_bf, eu_bf, d_i,
                                          g1u_bf, U_NUM, nullptr, nullptr, nullptr);
    spmm_csr_k<0><<<gi, blk, 0, stream>>>(ptr_i, ent_i, eu_bf, ei_bf, d_j,
                                          g1i_bf, I_NUM, nullptr, nullptr, nullptr);
    // layer 2 + combine + fused L2 partials (gcn_i first, then gcn_u in-place)
    spmm_csr_k<1><<<gi, blk, 0, stream>>>(ptr_i, ent_i, g1u_bf, g1i_bf, d_j,
                                          gcnI_bf, I_NUM, ei_bf, add_w, accI);
    spmm_csr_k<1><<<gu, blk, 0, stream>>>(ptr_u, ent_u, g1i_bf, g1u_bf, d_i,
                                          g1u_bf, U_NUM, eu_bf, add_w, accU);

    batch_mlp2_k<<<1024, blk, 0, stream>>>(user0, item0, g1u_bf, gcnI_bf,
                                           fw1, fb1, fw2, fb2, ub, ib, avg,
                                           ratings, sse);
    finalize2_k<<<1, blk, 0, stream>>>(accU, accI, sse, (float*)d_out);
}

// Round 7
// 1211.011 us; speedup vs baseline: 1.9210x; 1.4363x over previous
//
#include <hip/hip_runtime.h>

#define U_NUM 359347
#define I_NUM 292589
#define DDIM  64
#define NNZ_N 4000000
#define BATCH 32768
#define LAM_F 0.001f
#define ACC_SLOTS 2048

#define EPB   4096                          // edges per level-1 block
#define NBLK  ((NNZ_N + EPB - 1) / EPB)     // 977
#define NB_U  ((U_NUM + 1023) >> 10)        // 351
#define NB_I  ((I_NUM + 1023) >> 10)        // 286

__device__ __forceinline__ float leaky(float x) { return x > 0.f ? x : 0.1f * x; }

__device__ __forceinline__ unsigned short f2bf(float f) {
    unsigned b = __float_as_uint(f);
    b = (b + 0x7FFF + ((b >> 16) & 1)) >> 16;   // RNE
    return (unsigned short)b;
}
__device__ __forceinline__ float bf2f(unsigned short u) {
    return __uint_as_float((unsigned)u << 16);
}
__device__ __forceinline__ float bflo(unsigned u) { return __uint_as_float(u << 16); }
__device__ __forceinline__ float bfhi(unsigned u) { return __uint_as_float(u & 0xffff0000u); }

// ---------------------------------------------------------------------------
// fp32 -> bf16 bulk convert
// ---------------------------------------------------------------------------
__global__ __launch_bounds__(256) void f2bf_k(
    const float4* __restrict__ in, ushort4* __restrict__ out, size_t n4)
{
    size_t stride = (size_t)gridDim.x * 256;
    for (size_t i = (size_t)blockIdx.x * 256 + threadIdx.x; i < n4; i += stride) {
        float4 v = in[i];
        ushort4 o;
        o.x = f2bf(v.x); o.y = f2bf(v.y); o.z = f2bf(v.z); o.w = f2bf(v.w);
        out[i] = o;
    }
}

// ---------------------------------------------------------------------------
// Level-1: bucket histogram per block  (bucket = key >> 10)
// ---------------------------------------------------------------------------
__global__ __launch_bounds__(256) void l1hist_k(
    const int* __restrict__ keys, int* __restrict__ gh, int nb)
{
    __shared__ int h[512];
    for (int i = threadIdx.x; i < nb; i += 256) h[i] = 0;
    __syncthreads();
    int base = blockIdx.x * EPB;
    int end = min(base + EPB, NNZ_N);
    for (int e = base + threadIdx.x; e < end; e += 256)
        atomicAdd(&h[keys[e] >> 10], 1);
    __syncthreads();
    for (int i = threadIdx.x; i < nb; i += 256)
        gh[i * NBLK + blockIdx.x] = h[i];
}

__global__ __launch_bounds__(256) void scan1_k(int* __restrict__ a, int n, int* __restrict__ bsum)
{
    __shared__ int s[256];
    int t = threadIdx.x;
    int base = blockIdx.x * 1024 + t * 4;
    int v[4];
#pragma unroll
    for (int j = 0; j < 4; ++j) v[j] = (base + j < n) ? a[base + j] : 0;
    s[t] = v[0] + v[1] + v[2] + v[3];
    __syncthreads();
    for (int off = 1; off < 256; off <<= 1) {
        int x = (t >= off) ? s[t - off] : 0;
        __syncthreads();
        s[t] += x;
        __syncthreads();
    }
    if (t == 255) bsum[blockIdx.x] = s[255];
    int run = (t > 0) ? s[t - 1] : 0;
#pragma unroll
    for (int j = 0; j < 4; ++j) {
        if (base + j < n) a[base + j] = run;
        run += v[j];
    }
}

__global__ __launch_bounds__(512) void scan2_k(int* __restrict__ bsum, int nb)
{
    __shared__ int s[512];
    int t = threadIdx.x;
    int v = (t < nb) ? bsum[t] : 0;
    s[t] = v;
    __syncthreads();
    for (int off = 1; off < 512; off <<= 1) {
        int x = (t >= off) ? s[t - off] : 0;
        __syncthreads();
        s[t] += x;
        __syncthreads();
    }
    if (t < nb) bsum[t] = s[t] - v;   // exclusive
}

__global__ __launch_bounds__(256) void scan3_k(int* __restrict__ a, int n,
                                               const int* __restrict__ bsum)
{
    int add = bsum[blockIdx.x];
    int base = blockIdx.x * 1024 + threadIdx.x * 4;
#pragma unroll
    for (int j = 0; j < 4; ++j)
        if (base + j < n) a[base + j] += add;
}

__global__ __launch_bounds__(256) void l1scatter_k(
    const int* __restrict__ keys, const int* __restrict__ gh, int nb,
    int2* __restrict__ out)
{
    __shared__ int cur[512];
    for (int i = threadIdx.x; i < nb; i += 256) cur[i] = gh[i * NBLK + blockIdx.x];
    __syncthreads();
    int base = blockIdx.x * EPB;
    int end = min(base + EPB, NNZ_N);
    for (int e = base + threadIdx.x; e < end; e += 256) {
        int k = keys[e];
        int pos = atomicAdd(&cur[k >> 10], 1);
        out[pos] = make_int2(k, e);
    }
}

__global__ __launch_bounds__(256) void l2sort_k(
    const int2* __restrict__ tmp, const int* __restrict__ gh, int nb,
    const int* __restrict__ colArr, const float* __restrict__ valArr,
    int* __restrict__ ptr, int nrows, int2* __restrict__ ent)
{
    __shared__ int hist[1024];
    __shared__ int ssc[256];
    int b = blockIdx.x;
    int t = threadIdx.x;
    int bucket_base = gh[b * NBLK];
    int bucket_end  = (b == nb - 1) ? NNZ_N : gh[(b + 1) * NBLK];
    for (int i = t; i < 1024; i += 256) hist[i] = 0;
    __syncthreads();
    for (int e = bucket_base + t; e < bucket_end; e += 256)
        atomicAdd(&hist[tmp[e].x & 1023], 1);
    __syncthreads();
    int v0 = hist[t * 4], v1 = hist[t * 4 + 1], v2 = hist[t * 4 + 2], v3 = hist[t * 4 + 3];
    ssc[t] = v0 + v1 + v2 + v3;
    __syncthreads();
    for (int off = 1; off < 256; off <<= 1) {
        int x = (t >= off) ? ssc[t - off] : 0;
        __syncthreads();
        ssc[t] += x;
        __syncthreads();
    }
    int run = (t > 0) ? ssc[t - 1] : 0;
    int g0 = run, g1 = run + v0, g2 = g1 + v1, g3 = g2 + v2;
    hist[t * 4] = g0; hist[t * 4 + 1] = g1; hist[t * 4 + 2] = g2; hist[t * 4 + 3] = g3;
    int rbase = b << 10;
    if (rbase + t * 4 < nrows)     ptr[rbase + t * 4]     = bucket_base + g0;
    if (rbase + t * 4 + 1 < nrows) ptr[rbase + t * 4 + 1] = bucket_base + g1;
    if (rbase + t * 4 + 2 < nrows) ptr[rbase + t * 4 + 2] = bucket_base + g2;
    if (rbase + t * 4 + 3 < nrows) ptr[rbase + t * 4 + 3] = bucket_base + g3;
    if (b == nb - 1 && t == 0) ptr[nrows] = NNZ_N;
    __syncthreads();
    for (int e = bucket_base + t; e < bucket_end; e += 256) {
        int2 q = tmp[e];
        int pos = bucket_base + atomicAdd(&hist[q.x & 1023], 1);
        ent[pos] = make_int2(colArr[q.y], __float_as_int(valArr[q.y]));
    }
}

// ---------------------------------------------------------------------------
// CSR SpMM over bf16 matrices (unchanged from round 6)
// ---------------------------------------------------------------------------
template <int MODE>
__global__ __launch_bounds__(256) void spmm_csr_k(
    const int* __restrict__ ptr, const int2* __restrict__ ent,
    const unsigned short* __restrict__ x, const unsigned short* base,
    const float* __restrict__ deg, unsigned short* out, int nrows,
    const unsigned short* __restrict__ embed, const float* __restrict__ add_w,
    float* __restrict__ accArr)
{
    int wv = threadIdx.x >> 6, lane = threadIdx.x & 63;
    int r = blockIdx.x * 4 + wv;
    __shared__ float ssum[4];
    if (r < nrows) {
        int s0 = __builtin_amdgcn_readfirstlane(ptr[r]);
        int e0 = __builtin_amdgcn_readfirstlane(ptr[r + 1]);
        float a0 = 0.f, a1 = 0.f, a2 = 0.f, a3 = 0.f;
        int k = s0;
        for (; k + 4 <= e0; k += 4) {
            int2 q0 = ent[k], q1 = ent[k + 1], q2 = ent[k + 2], q3 = ent[k + 3];
            float x0 = bf2f(x[(size_t)q0.x * DDIM + lane]);
            float x1 = bf2f(x[(size_t)q1.x * DDIM + lane]);
            float x2 = bf2f(x[(size_t)q2.x * DDIM + lane]);
            float x3 = bf2f(x[(size_t)q3.x * DDIM + lane]);
            a0 = fmaf(__int_as_float(q0.y), x0, a0);
            a1 = fmaf(__int_as_float(q1.y), x1, a1);
            a2 = fmaf(__int_as_float(q2.y), x2, a2);
            a3 = fmaf(__int_as_float(q3.y), x3, a3);
        }
        for (; k < e0; ++k) {
            int2 q = ent[k];
            a0 = fmaf(__int_as_float(q.y), bf2f(x[(size_t)q.x * DDIM + lane]), a0);
        }
        float acc = (a0 + a1) + (a2 + a3);
        float bb = bf2f(base[(size_t)r * DDIM + lane]);
        float o = fmaxf(fmaf(bb, deg[r], acc), 0.f);
        if (MODE == 0) {
            out[(size_t)r * DDIM + lane] = f2bf(o);
        } else {
            float g = fmaf(add_w[0], bf2f(embed[(size_t)r * DDIM + lane]),
                           fmaf(add_w[1], bb, add_w[2] * o));
            out[(size_t)r * DDIM + lane] = f2bf(g);
            float sq = g * g;
            for (int off = 32; off; off >>= 1) sq += __shfl_down(sq, off);
            if (lane == 0) ssum[wv] = sq;
        }
    } else if (MODE == 1) {
        if (lane == 0) ssum[wv] = 0.f;
    }
    if (MODE == 1) {
        __syncthreads();
        if (threadIdx.x == 0)
            atomicAdd(&accArr[blockIdx.x & (ACC_SLOTS - 1)],
                      ssum[0] + ssum[1] + ssum[2] + ssum[3]);
    }
}

// ---------------------------------------------------------------------------
// MLP as block-tiled VALU GEMM. One block = 64 samples of one side.
// GEMM1: X[64x64] @ w1^T -> H[64x128], leaky; GEMM2: H @ w2^T -> O[64x64],
// leaky; O written bf16 to global. Thread tile: 4 samples x 8 (G1) / 4 (G2).
// LDS transposed [k][s] layouts give conflict-free / 2-way reads.
// ---------------------------------------------------------------------------
__global__ __launch_bounds__(256) void mlp_k(
    const int* __restrict__ user0, const int* __restrict__ item0,
    const unsigned short* __restrict__ gcnU, const unsigned short* __restrict__ gcnI,
    const float* __restrict__ fw1, const float* __restrict__ fb1,
    const float* __restrict__ fw2, const float* __restrict__ fb2,
    unsigned short* __restrict__ ou, unsigned short* __restrict__ oi)
{
    __shared__ unsigned short xs[64][72];    // [k][s]  9216B
    __shared__ unsigned short w1s[128][68];  // [o][k] 17408B
    __shared__ unsigned short w2s[64][140];  // [o][k] 17920B
    __shared__ unsigned short hs[128][72];   // [k][s] 18432B
    __shared__ float b1s[128];
    __shared__ float b2s[64];

    int t = threadIdx.x;
    int side = blockIdx.x >> 9;              // 512 tiles per side
    int tile = blockIdx.x & 511;
    const int* sel = side ? item0 : user0;
    const unsigned short* gcn = side ? gcnI : gcnU;
    unsigned short* outp = side ? oi : ou;

    // ---- stage X transposed: thread (r = t>>2, c = t&3) loads 16 bf16 ----
    {
        int r = t >> 2, c = t & 3;
        int idx = sel[tile * 64 + r];
        const ushort4* src = (const ushort4*)(gcn + (size_t)idx * 64 + c * 16);
        ushort4 v0 = src[0], v1 = src[1], v2 = src[2], v3 = src[3];
        int k0 = c * 16;
        xs[k0 +  0][r] = v0.x; xs[k0 +  1][r] = v0.y; xs[k0 +  2][r] = v0.z; xs[k0 +  3][r] = v0.w;
        xs[k0 +  4][r] = v1.x; xs[k0 +  5][r] = v1.y; xs[k0 +  6][r] = v1.z; xs[k0 +  7][r] = v1.w;
        xs[k0 +  8][r] = v2.x; xs[k0 +  9][r] = v2.y; xs[k0 + 10][r] = v2.z; xs[k0 + 11][r] = v2.w;
        xs[k0 + 12][r] = v3.x; xs[k0 + 13][r] = v3.y; xs[k0 + 14][r] = v3.z; xs[k0 + 15][r] = v3.w;
    }
    // ---- stage weights (bf16) ----
#pragma unroll
    for (int i = 0; i < 8; ++i) {
        int flat = i * 1024 + t * 4;
        float4 w = *(const float4*)(fw1 + flat);
        int o = flat >> 6, k = flat & 63;
        *(unsigned*)&w1s[o][k]     = (unsigned)f2bf(w.x) | ((unsigned)f2bf(w.y) << 16);
        *(unsigned*)&w1s[o][k + 2] = (unsigned)f2bf(w.z) | ((unsigned)f2bf(w.w) << 16);
        float4 u = *(const float4*)(fw2 + flat);
        int o2 = flat >> 7, k2 = flat & 127;
        *(unsigned*)&w2s[o2][k2]     = (unsigned)f2bf(u.x) | ((unsigned)f2bf(u.y) << 16);
        *(unsigned*)&w2s[o2][k2 + 2] = (unsigned)f2bf(u.z) | ((unsigned)f2bf(u.w) << 16);
    }
    if (t < 128) b1s[t] = fb1[t];
    if (t < 64)  b2s[t] = fb2[t];
    __syncthreads();

    int sg = t & 15, og = t >> 4;   // samples 4sg..4sg+3

    // ---- GEMM1: outputs og*8..og*8+7 ----
    float acc[4][8];
#pragma unroll
    for (int i = 0; i < 4; ++i)
#pragma unroll
        for (int j = 0; j < 8; ++j) acc[i][j] = 0.f;

    for (int kc = 0; kc < 64; kc += 4) {
        uint2 xp0 = *(const uint2*)&xs[kc    ][sg * 4];
        uint2 xp1 = *(const uint2*)&xs[kc + 1][sg * 4];
        uint2 xp2 = *(const uint2*)&xs[kc + 2][sg * 4];
        uint2 xp3 = *(const uint2*)&xs[kc + 3][sg * 4];
        float x0[4] = { bflo(xp0.x), bfhi(xp0.x), bflo(xp0.y), bfhi(xp0.y) };
        float x1[4] = { bflo(xp1.x), bfhi(xp1.x), bflo(xp1.y), bfhi(xp1.y) };
        float x2[4] = { bflo(xp2.x), bfhi(xp2.x), bflo(xp2.y), bfhi(xp2.y) };
        float x3[4] = { bflo(xp3.x), bfhi(xp3.x), bflo(xp3.y), bfhi(xp3.y) };
#pragma unroll
        for (int j = 0; j < 8; ++j) {
            uint2 wp = *(const uint2*)&w1s[og * 8 + j][kc];
            float w0 = bflo(wp.x), w1v = bfhi(wp.x), w2v = bflo(wp.y), w3v = bfhi(wp.y);
#pragma unroll
            for (int i = 0; i < 4; ++i) {
                acc[i][j] = fmaf(x0[i], w0,  acc[i][j]);
                acc[i][j] = fmaf(x1[i], w1v, acc[i][j]);
                acc[i][j] = fmaf(x2[i], w2v, acc[i][j]);
                acc[i][j] = fmaf(x3[i], w3v, acc[i][j]);
            }
        }
    }
    // epilogue 1: bias + leaky -> hs bf16 transposed
#pragma unroll
    for (int j = 0; j < 8; ++j) {
        int o = og * 8 + j;
        float b = b1s[o];
        float h0 = leaky(acc[0][j] + b), h1 = leaky(acc[1][j] + b);
        float h2 = leaky(acc[2][j] + b), h3 = leaky(acc[3][j] + b);
        *(unsigned*)&hs[o][sg * 4]     = (unsigned)f2bf(h0) | ((unsigned)f2bf(h1) << 16);
        *(unsigned*)&hs[o][sg * 4 + 2] = (unsigned)f2bf(h2) | ((unsigned)f2bf(h3) << 16);
    }
    __syncthreads();

    // ---- GEMM2: outputs og*4..og*4+3, K=128 ----
    float acc2[4][4];
#pragma unroll
    for (int i = 0; i < 4; ++i)
#pragma unroll
        for (int j = 0; j < 4; ++j) acc2[i][j] = 0.f;

    for (int kc = 0; kc < 128; kc += 4) {
        uint2 hp0 = *(const uint2*)&hs[kc    ][sg * 4];
        uint2 hp1 = *(const uint2*)&hs[kc + 1][sg * 4];
        uint2 hp2 = *(const uint2*)&hs[kc + 2][sg * 4];
        uint2 hp3 = *(const uint2*)&hs[kc + 3][sg * 4];
        float h0[4] = { bflo(hp0.x), bfhi(hp0.x), bflo(hp0.y), bfhi(hp0.y) };
        float h1[4] = { bflo(hp1.x), bfhi(hp1.x), bflo(hp1.y), bfhi(hp1.y) };
        float h2[4] = { bflo(hp2.x), bfhi(hp2.x), bflo(hp2.y), bfhi(hp2.y) };
        float h3[4] = { bflo(hp3.x), bfhi(hp3.x), bflo(hp3.y), bfhi(hp3.y) };
#pragma unroll
        for (int j = 0; j < 4; ++j) {
            uint2 wp = *(const uint2*)&w2s[og * 4 + j][kc];
            float w0 = bflo(wp.x), w1v = bfhi(wp.x), w2v = bflo(wp.y), w3v = bfhi(wp.y);
#pragma unroll
            for (int i = 0; i < 4; ++i) {
                acc2[i][j] = fmaf(h0[i], w0,  acc2[i][j]);
                acc2[i][j] = fmaf(h1[i], w1v, acc2[i][j]);
                acc2[i][j] = fmaf(h2[i], w2v, acc2[i][j]);
                acc2[i][j] = fmaf(h3[i], w3v, acc2[i][j]);
            }
        }
    }
    // epilogue 2: bias + leaky -> global O bf16
#pragma unroll
    for (int i = 0; i < 4; ++i) {
        float o0 = leaky(acc2[i][0] + b2s[og * 4 + 0]);
        float o1 = leaky(acc2[i][1] + b2s[og * 4 + 1]);
        float o2 = leaky(acc2[i][2] + b2s[og * 4 + 2]);
        float o3 = leaky(acc2[i][3] + b2s[og * 4 + 3]);
        uint2 pp;
        pp.x = (unsigned)f2bf(o0) | ((unsigned)f2bf(o1) << 16);
        pp.y = (unsigned)f2bf(o2) | ((unsigned)f2bf(o3) << 16);
        *(uint2*)(outp + ((size_t)(tile * 64 + sg * 4 + i) * 64 + og * 4)) = pp;
    }
}

// ---------------------------------------------------------------------------
// Pairwise dot + biases + SSE. 4 threads per sample.
// ---------------------------------------------------------------------------
__global__ __launch_bounds__(256) void dot_sse_k(
    const unsigned short* __restrict__ ou, const unsigned short* __restrict__ oi,
    const int* __restrict__ user0, const int* __restrict__ item0,
    const float* __restrict__ ub, const float* __restrict__ ib,
    const float* __restrict__ avg, const float* __restrict__ ratings,
    float* __restrict__ sse)
{
    int g = blockIdx.x * 256 + threadIdx.x;
    int b = g >> 2, q = g & 3;
    const uint4* pu = (const uint4*)(ou + (size_t)b * 64 + q * 16);
    const uint4* pi = (const uint4*)(oi + (size_t)b * 64 + q * 16);
    uint4 a0 = pu[0], a1 = pu[1];
    uint4 c0 = pi[0], c1 = pi[1];
    float s = 0.f;
#define DOTP(ua, uc) { s = fmaf(bflo(ua), bflo(uc), s); s = fmaf(bfhi(ua), bfhi(uc), s); }
    DOTP(a0.x, c0.x) DOTP(a0.y, c0.y) DOTP(a0.z, c0.z) DOTP(a0.w, c0.w)
    DOTP(a1.x, c1.x) DOTP(a1.y, c1.y) DOTP(a1.z, c1.z) DOTP(a1.w, c1.w)
#undef DOTP
    s += __shfl_xor(s, 1);
    s += __shfl_xor(s, 2);
    float contrib = 0.f;
    if (q == 0) {
        float pred = s + ub[user0[b]] + ib[item0[b]] + avg[0];
        float d = pred - ratings[b];
        contrib = d * d;
    }
    for (int off = 32; off; off >>= 1) contrib += __shfl_down(contrib, off);
    __shared__ float wsum[4];
    int lane = threadIdx.x & 63, wv = threadIdx.x >> 6;
    if (lane == 0) wsum[wv] = contrib;
    __syncthreads();
    if (threadIdx.x == 0)
        atomicAdd(sse, wsum[0] + wsum[1] + wsum[2] + wsum[3]);
}

__global__ __launch_bounds__(256) void finalize2_k(
    const float* __restrict__ accU, const float* __restrict__ accI,
    const float* __restrict__ sse, float* __restrict__ out)
{
    int t = threadIdx.x;
    float su = 0.f, si = 0.f;
    for (int i = t; i < ACC_SLOTS; i += 256) { su += accU[i]; si += accI[i]; }
    for (int off = 32; off; off >>= 1) {
        su += __shfl_down(su, off);
        si += __shfl_down(si, off);
    }
    __shared__ float s[8];
    int wv = t >> 6, lane = t & 63;
    if (lane == 0) { s[wv] = su; s[wv + 4] = si; }
    __syncthreads();
    if (t == 0) {
        float SU = s[0] + s[1] + s[2] + s[3];
        float SI = s[4] + s[5] + s[6] + s[7];
        out[0] = sse[0] / (float)BATCH
               + LAM_F * (SU / (float)((double)U_NUM * 64.0))
               + LAM_F * (SI / (float)((double)I_NUM * 64.0));
    }
}

// ---------------------------------------------------------------------------

extern "C" void kernel_launch(void* const* d_in, const int* in_sizes, int n_in,
                              void* d_out, int out_size, void* d_ws, size_t ws_size,
                              hipStream_t stream)
{
    const int*   ui_rows = (const int*)d_in[0];
    const int*   ui_cols = (const int*)d_in[1];
    const float* ui_vals = (const float*)d_in[2];
    const float* iu_vals = (const float*)d_in[3];
    const float* d_i     = (const float*)d_in[4];
    const float* d_j     = (const float*)d_in[5];
    const float* eu      = (const float*)d_in[6];
    const float* ei      = (const float*)d_in[7];
    const float* add_w   = (const float*)d_in[8];
    const float* fw1     = (const float*)d_in[9];
    const float* fb1     = (const float*)d_in[10];
    const float* fw2     = (const float*)d_in[11];
    const float* fb2     = (const float*)d_in[12];
    const float* ub      = (const float*)d_in[13];
    const float* ib      = (const float*)d_in[14];
    const float* avg     = (const float*)d_in[15];
    const int*   user0   = (const int*)d_in[16];
    const int*   item0   = (const int*)d_in[17];
    const float* ratings = (const float*)d_in[18];

    const size_t U64 = (size_t)U_NUM * DDIM;
    const size_t I64 = (size_t)I_NUM * DDIM;

    // ---- workspace layout (~313 MB; budget known >= 334 MB) ----
    int2* ent_u = (int2*)d_ws;                       // NNZ
    int2* ent_i = ent_u + NNZ_N;                     // NNZ
    int2* tmpb  = ent_i + NNZ_N;                     // NNZ
    int*  gh    = (int*)(tmpb + NNZ_N);              // NB_U * NBLK (max)
    int*  bsum  = gh + (size_t)NB_U * NBLK;          // 512
    int*  ptr_u = bsum + 512;                        // U+1
    int*  ptr_i = ptr_u + (U_NUM + 1);               // I+1
    float* accU = (float*)(ptr_i + (I_NUM + 1));     // ACC_SLOTS
    float* accI = accU + ACC_SLOTS;                  // ACC_SLOTS
    float* sse  = accI + ACC_SLOTS;                  // 4
    unsigned short* eu_bf   = (unsigned short*)(sse + 4);  // U64
    unsigned short* ei_bf   = eu_bf + U64;                 // I64
    unsigned short* g1u_bf  = ei_bf + I64;                 // U64 (becomes gcnU)
    unsigned short* g1i_bf  = g1u_bf + U64;                // I64
    unsigned short* gcnI_bf = g1i_bf + I64;                // I64
    unsigned short* ou_bf   = gcnI_bf + I64;               // BATCH*64
    unsigned short* oi_bf   = ou_bf + (size_t)BATCH * 64;  // BATCH*64
    (void)ws_size;

    dim3 blk(256);
    int gu = (U_NUM + 3) / 4, gi = (I_NUM + 3) / 4;

    hipMemsetAsync(accU, 0, (2 * ACC_SLOTS + 4) * sizeof(float), stream);

    f2bf_k<<<2048, blk, 0, stream>>>((const float4*)eu, (ushort4*)eu_bf, U64 / 4);
    f2bf_k<<<2048, blk, 0, stream>>>((const float4*)ei, (ushort4*)ei_bf, I64 / 4);

    // ---- user-side CSR (key = ui_rows) ----
    {
        int n = NB_U * NBLK;
        int nb1 = (n + 1023) / 1024;
        l1hist_k<<<NBLK, blk, 0, stream>>>(ui_rows, gh, NB_U);
        scan1_k<<<nb1, blk, 0, stream>>>(gh, n, bsum);
        scan2_k<<<1, 512, 0, stream>>>(bsum, nb1);
        scan3_k<<<nb1, blk, 0, stream>>>(gh, n, bsum);
        l1scatter_k<<<NBLK, blk, 0, stream>>>(ui_rows, gh, NB_U, tmpb);
        l2sort_k<<<NB_U, blk, 0, stream>>>(tmpb, gh, NB_U, ui_cols, ui_vals,
                                           ptr_u, U_NUM, ent_u);
    }
    // ---- item-side CSR (key = ui_cols) ----
    {
        int n = NB_I * NBLK;
        int nb1 = (n + 1023) / 1024;
        l1hist_k<<<NBLK, blk, 0, stream>>>(ui_cols, gh, NB_I);
        scan1_k<<<nb1, blk, 0, stream>>>(gh, n, bsum);
        scan2_k<<<1, 512, 0, stream>>>(bsum, nb1);
        scan3_k<<<nb1, blk, 0, stream>>>(gh, n, bsum);
        l1scatter_k<<<NBLK, blk, 0, stream>>>(ui_cols, gh, NB_I, tmpb);
        l2sort_k<<<NB_I, blk, 0, stream>>>(tmpb, gh, NB_I, ui_rows, iu_vals,
                                           ptr_i, I_NUM, ent_i);
    }

    // ---- GCN layers ----
    spmm_csr_k<0><<<gu, blk, 0, stream>>>(ptr_u, ent_u, ei_bf, eu_bf, d_i,
                                          g1u_bf, U_NUM, nullptr, nullptr, nullptr);
    spmm_csr_k<0><<<gi, blk, 0, stream>>>(ptr_i, ent_i, eu_bf, ei_bf, d_j,
                                          g1i_bf, I_NUM, nullptr, nullptr, nullptr);
    spmm_csr_k<1><<<gi, blk, 0, stream>>>(ptr_i, ent_i, g1u_bf, g1i_bf, d_j,
                                          gcnI_bf, I_NUM, ei_bf, add_w, accI);
    spmm_csr_k<1><<<gu, blk, 0, stream>>>(ptr_u, ent_u, g1i_bf, g1u_bf, d_i,
                                          g1u_bf, U_NUM, eu_bf, add_w, accU);

    // ---- MLP (tiled GEMM) + dot/SSE ----
    mlp_k<<<1024, blk, 0, stream>>>(user0, item0, g1u_bf, gcnI_bf,
                                    fw1, fb1, fw2, fb2, ou_bf, oi_bf);
    dot_sse_k<<<BATCH * 4 / 256, blk, 0, stream>>>(ou_bf, oi_bf, user0, item0,
                                                   ub, ib, avg, ratings, sse);
    finalize2_k<<<1, blk, 0, stream>>>(accU, accI, sse, (float*)d_out);
}